// Round 4
// baseline (1120.551 us; speedup 1.0000x reference)
//
#include <hip/hip_runtime.h>
#include <hip/hip_cooperative_groups.h>
#include <cstdint>
#include <cstddef>

namespace cg = cooperative_groups;

#define E_DIM   1024
#define B_DIM   1024
#define T_STEPS 10
#define OUT_DIM 34
#define OUT_PAD 48
#define HSTR    24           // h-transpose LDS row stride (16 cols + pad)
#define W_ELEMS (64 * 1024)  // W slice: 64 rows x 1024 k (128 KB)
#define DYN_LDS (W_ELEMS * 2 + 256 * HSTR * 2)   // 131072 + 12288 = 143360 B

typedef __attribute__((ext_vector_type(4))) float  f32x4;
typedef __attribute__((ext_vector_type(8))) __bf16 bf16x8;

__device__ __forceinline__ unsigned short f2bf(float f) {
    unsigned int u = __float_as_uint(f);
    u = (u + 0x7FFFu + ((u >> 16) & 1u)) >> 16;   // round-to-nearest-even
    return (unsigned short)u;
}
__device__ __forceinline__ float sigmoid_(float x) { return 1.0f / (1.0f + __expf(-x)); }
__device__ __forceinline__ float tanh_(float x)    { return 2.0f / (1.0f + __expf(-2.0f * x)) - 1.0f; }

// Permutation: perm row n = 64*eb + 16*g + j  ->  gate g = (n>>4)&3, e = 16*eb + j.
// Block bn owns perm rows [64bn, 64bn+64) = 4 gates x 16 e-values; gate index == nt tile,
// so the LSTM epilogue is lane-local (acc[mt][gate][r]).
__global__ void prep_weights(const float* __restrict__ W_ih, const float* __restrict__ W_hh,
                             const float* __restrict__ b_ih, const float* __restrict__ b_hh,
                             unsigned short* __restrict__ Wsum, unsigned short* __restrict__ Whh,
                             float* __restrict__ bperm) {
    const int n = blockIdx.x;                       // 0..4095 permuted row
    const int g = (n >> 4) & 3;
    const int e = ((n >> 6) << 4) | (n & 15);
    const int srow = g * E_DIM + e;
    const size_t src = (size_t)srow * E_DIM;
    const int k = threadIdx.x * 4;
    float4 wi = *(const float4*)(W_ih + src + k);
    float4 wh = *(const float4*)(W_hh + src + k);
    const size_t dst = (size_t)n * E_DIM + k;
    Wsum[dst + 0] = f2bf(wi.x + wh.x);
    Wsum[dst + 1] = f2bf(wi.y + wh.y);
    Wsum[dst + 2] = f2bf(wi.z + wh.z);
    Wsum[dst + 3] = f2bf(wi.w + wh.w);
    Whh[dst + 0] = f2bf(wh.x);
    Whh[dst + 1] = f2bf(wh.y);
    Whh[dst + 2] = f2bf(wh.z);
    Whh[dst + 3] = f2bf(wh.w);
    if (threadIdx.x == 0) bperm[n] = b_ih[srow] + b_hh[srow];
}

// h0 -> bf16 into hs slot 0; W_out -> bf16 padded to 48 rows
__global__ void prep_state(const float* __restrict__ h0, const float* __restrict__ W_out,
                           unsigned short* __restrict__ hbuf, unsigned short* __restrict__ Woutp) {
    const int b = blockIdx.x;
    const int t = threadIdx.x;
    if (b < 1024) {
        const size_t i = ((size_t)b * 256 + t) * 4;
        float4 hv = *(const float4*)(h0 + i);
        hbuf[i + 0] = f2bf(hv.x);
        hbuf[i + 1] = f2bf(hv.y);
        hbuf[i + 2] = f2bf(hv.z);
        hbuf[i + 3] = f2bf(hv.w);
    } else {
        const int o = b - 1024;                     // 0..47
        const int k = t * 4;
        float4 w = make_float4(0.f, 0.f, 0.f, 0.f);
        if (o < OUT_DIM) w = *(const float4*)(W_out + (size_t)o * E_DIM + k);
        const size_t dst = (size_t)o * E_DIM + k;
        Woutp[dst + 0] = f2bf(w.x);
        Woutp[dst + 1] = f2bf(w.y);
        Woutp[dst + 2] = f2bf(w.z);
        Woutp[dst + 3] = f2bf(w.w);
    }
}

// All 10 LSTM steps in one cooperative kernel.
// Grid (64, 4) = 256 blocks (1/CU), 512 threads = 8 waves.
// Block (bn,bm): 64 permuted N-rows (4 gates x 16 e) x 256 batch rows.
// W slice (128 KB) staged in LDS once (Whh at t=0, Wsum at t=1, reused t=1..9).
// Cell state lives in registers for all 10 steps. grid.sync() between steps.
__global__ __launch_bounds__(512, 1) void lstm_all(
    const unsigned short* Whh,     // [4096][1024] bf16 permuted
    const unsigned short* Wsum,    // [4096][1024] bf16 permuted
    const float* bp,               // [4096] permuted bias
    const float* c0,               // [1024][1024] f32 initial cell state (raw layout)
    unsigned short* hs)            // [11][1024][1024] bf16: slot 0 = h0, slot t+1 = step-t output
{
    extern __shared__ __align__(16) unsigned short smem[];
    unsigned short* Ws = smem;                 // 64 x 1024, swizzled (128 KB)
    unsigned short* Ht = smem + W_ELEMS;       // 256 x HSTR (12 KB)

    const int tid  = threadIdx.x;
    const int wave = tid >> 6;
    const int lane = tid & 63;
    const int bn = blockIdx.x;
    const int bm = blockIdx.y;
    const int j  = lane & 15;
    const int q  = lane >> 4;
    const int j7 = j & 7;

    // biases (gate-split, lane-local)
    const int nb = bn * 64 + j;
    const float bi = bp[nb +  0];
    const float bf = bp[nb + 16];
    const float bg = bp[nb + 32];
    const float bo = bp[nb + 48];

    // cell state -> registers (scalar gather, once per kernel)
    float cc[2][4];
#pragma unroll
    for (int mt = 0; mt < 2; ++mt)
#pragma unroll
        for (int r = 0; r < 4; ++r) {
            const int m = bm * 256 + wave * 32 + mt * 16 + q * 4 + r;
            cc[mt][r] = c0[(size_t)m * E_DIM + bn * 16 + j];
        }

    cg::grid_group grid = cg::this_grid();

    for (int t = 0; t < T_STEPS; ++t) {
        const unsigned short* Asrc = hs + (size_t)t * (B_DIM * E_DIM);
        const unsigned short* arow0 = Asrc + (size_t)(bm * 256 + wave * 32 + j) * E_DIM + q * 8;
        const unsigned short* arow1 = arow0 + (size_t)16 * E_DIM;

        // prefetch first 4 A k-steps (overlaps W staging when it happens)
        uint4 ra[4][2];
#pragma unroll
        for (int p = 0; p < 4; ++p) {
            ra[p][0] = *(const uint4*)(arow0 + p * 32);
            ra[p][1] = *(const uint4*)(arow1 + p * 32);
        }

        if (t <= 1) {
            // stage W slice (full K): 64 rows x 128 chunks(8 elem), chunk c at c^(row&7)
            const unsigned short* wrow = ((t == 0) ? Whh : Wsum) + (size_t)(bn * 64) * E_DIM;
            __syncthreads();
#pragma unroll
            for (int i = 0; i < 16; ++i) {
                const int s = i * 512 + tid;
                const int row = s >> 7, c = s & 127;
                uint4 w = *(const uint4*)(wrow + (size_t)row * E_DIM + c * 8);
                *(uint4*)(Ws + row * 1024 + ((c ^ (row & 7)) << 3)) = w;
            }
            __syncthreads();
        }

        f32x4 acc[2][4];
#pragma unroll
        for (int a = 0; a < 2; ++a)
#pragma unroll
            for (int b = 0; b < 4; ++b) acc[a][b] = (f32x4){0.f, 0.f, 0.f, 0.f};

        // barrier-free K-loop: K=1024 in 32 steps of 32
#pragma unroll
        for (int ks = 0; ks < 32; ++ks) {
            bf16x8 av0 = __builtin_bit_cast(bf16x8, ra[ks & 3][0]);
            bf16x8 av1 = __builtin_bit_cast(bf16x8, ra[ks & 3][1]);
            const int coff = ((ks * 4 + q) ^ j7) << 3;   // same for all nt (row&7 == j&7)
            bf16x8 bv[4];
#pragma unroll
            for (int nt = 0; nt < 4; ++nt)
                bv[nt] = *(const bf16x8*)(Ws + (nt * 16 + j) * 1024 + coff);
#pragma unroll
            for (int nt = 0; nt < 4; ++nt) {
                acc[0][nt] = __builtin_amdgcn_mfma_f32_16x16x32_bf16(av0, bv[nt], acc[0][nt], 0, 0, 0);
                acc[1][nt] = __builtin_amdgcn_mfma_f32_16x16x32_bf16(av1, bv[nt], acc[1][nt], 0, 0, 0);
            }
            if (ks < 28) {                  // keep the 4-deep A pipeline full
                ra[ks & 3][0] = *(const uint4*)(arow0 + (ks + 4) * 32);
                ra[ks & 3][1] = *(const uint4*)(arow1 + (ks + 4) * 32);
            }
        }

        // ---- Epilogue: nt is the gate index (i,f,g,o); cell state stays in regs ----
        __syncthreads();                    // prior Ht reads (t-1 store) done before rewrite
#pragma unroll
        for (int mt = 0; mt < 2; ++mt) {
#pragma unroll
            for (int r = 0; r < 4; ++r) {
                const float iv = sigmoid_(acc[mt][0][r] + bi);
                const float fv = sigmoid_(acc[mt][1][r] + bf);
                const float gv = tanh_(acc[mt][2][r] + bg);
                const float ov = sigmoid_(acc[mt][3][r] + bo);
                const float cn = fv * cc[mt][r] + iv * gv;
                cc[mt][r] = cn;
                const int rowl = wave * 32 + mt * 16 + q * 4 + r;   // 0..255
                Ht[rowl * HSTR + j] = f2bf(ov * tanh_(cn));
            }
        }
        __syncthreads();

        // coalesced h store: 2 threads per row, 16B each
        {
            const int row = tid >> 1, part = tid & 1;
            uint4 v = *(const uint4*)(Ht + row * HSTR + part * 8);
            *(uint4*)(hs + (size_t)(t + 1) * (B_DIM * E_DIM)
                         + (size_t)(bm * 256 + row) * E_DIM + bn * 16 + part * 8) = v;
        }

        __threadfence();
        if (t < T_STEPS - 1) grid.sync();   // next step's A-reads need all blocks' h
    }
}

// Output projection: out[b,t,o] = hs[t+1][b][:] . Wo[o][:] + b_out[o]
// Grid (32, 10) = 320 blocks, 256 thr = 4 waves; wave w covers K-quarter [w*256,+256),
// block covers 32 batch rows x 48 (padded) outputs; cross-wave LDS reduction.
__global__ __launch_bounds__(256) void proj_kernel(
    const unsigned short* __restrict__ Hs,   // [T][B][E] bf16 (slot 1 of hs)
    const unsigned short* __restrict__ Wo,   // [48][E] bf16 (rows >=34 zero)
    const float* __restrict__ b_out,         // [34]
    float* __restrict__ Out)                 // [B][T][34]
{
    __shared__ float red[4][32][OUT_PAD];    // 24 KB

    const int tid = threadIdx.x, wave = tid >> 6, lane = tid & 63;
    const int j = lane & 15, q = lane >> 4;
    const int t  = blockIdx.y;
    const int bb = blockIdx.x;
    const unsigned short* Hbase = Hs + ((size_t)t * B_DIM + (size_t)bb * 32) * E_DIM;
    const int k0 = wave * 256;

    f32x4 acc[2][3];
#pragma unroll
    for (int a = 0; a < 2; ++a)
#pragma unroll
        for (int b = 0; b < 3; ++b) acc[a][b] = (f32x4){0.f, 0.f, 0.f, 0.f};

#pragma unroll
    for (int kk = 0; kk < 256; kk += 32) {
        const int kc = k0 + kk + q * 8;
        bf16x8 av[2], bv[3];
#pragma unroll
        for (int mt = 0; mt < 2; ++mt)
            av[mt] = *(const bf16x8*)(Hbase + (size_t)(mt * 16 + j) * E_DIM + kc);
#pragma unroll
        for (int nt = 0; nt < 3; ++nt)
            bv[nt] = *(const bf16x8*)(Wo + (size_t)(nt * 16 + j) * E_DIM + kc);
#pragma unroll
        for (int mt = 0; mt < 2; ++mt)
#pragma unroll
            for (int nt = 0; nt < 3; ++nt)
                acc[mt][nt] = __builtin_amdgcn_mfma_f32_16x16x32_bf16(av[mt], bv[nt], acc[mt][nt], 0, 0, 0);
    }

#pragma unroll
    for (int mt = 0; mt < 2; ++mt)
#pragma unroll
        for (int nt = 0; nt < 3; ++nt)
#pragma unroll
            for (int r = 0; r < 4; ++r)
                red[wave][mt * 16 + q * 4 + r][nt * 16 + j] = acc[mt][nt][r];
    __syncthreads();

#pragma unroll
    for (int ii = 0; ii < 6; ++ii) {
        const int idx = tid * 6 + ii;            // 0..1535 = 32 rows x 48 outs
        const int row = idx / OUT_PAD, o = idx % OUT_PAD;
        if (o < OUT_DIM) {
            const float s = red[0][row][o] + red[1][row][o] + red[2][row][o] + red[3][row][o];
            Out[((size_t)(bb * 32 + row) * T_STEPS + t) * OUT_DIM + o] = s + b_out[o];
        }
    }
}

extern "C" void kernel_launch(void* const* d_in, const int* in_sizes, int n_in,
                              void* d_out, int out_size, void* d_ws, size_t ws_size,
                              hipStream_t stream) {
    (void)in_sizes; (void)n_in; (void)out_size; (void)ws_size;
    const float* h     = (const float*)d_in[0];
    const float* c     = (const float*)d_in[1];
    const float* W_ih  = (const float*)d_in[2];
    const float* W_hh  = (const float*)d_in[3];
    const float* b_ih  = (const float*)d_in[4];
    const float* b_hh  = (const float*)d_in[5];
    const float* W_out = (const float*)d_in[6];
    const float* b_out = (const float*)d_in[7];
    float* out = (float*)d_out;

    char* ws = (char*)d_ws;
    unsigned short* Wsum  = (unsigned short*)(ws + 0);          //  8 MB
    unsigned short* Whh   = (unsigned short*)(ws + 8388608);    //  8 MB
    float*          bperm = (float*)(ws + 16777216);            // 16 KB
    unsigned short* Woutp = (unsigned short*)(ws + 16842752);   // 96 KB
    unsigned short* hs    = (unsigned short*)(ws + 16973824);   // 22 MB: slot0=h0, slots1..10=outputs

    prep_weights<<<4096, 256, 0, stream>>>(W_ih, W_hh, b_ih, b_hh, Wsum, Whh, bperm);
    prep_state<<<1072, 256, 0, stream>>>(h, W_out, hs, Woutp);

    static bool attr_done = false;
    if (!attr_done) {   // host-side attribute set; idempotent, not a stream op
        hipFuncSetAttribute((const void*)lstm_all,
                            hipFuncAttributeMaxDynamicSharedMemorySize, DYN_LDS);
        attr_done = true;
    }

    {
        const unsigned short* whh_p  = Whh;
        const unsigned short* wsum_p = Wsum;
        const float*          bp_p   = bperm;
        const float*          c_p    = c;
        unsigned short*       hs_p   = hs;
        void* args[] = {(void*)&whh_p, (void*)&wsum_p, (void*)&bp_p, (void*)&c_p, (void*)&hs_p};
        hipLaunchCooperativeKernel((const void*)lstm_all, dim3(64, 4), dim3(512),
                                   args, DYN_LDS, stream);
    }

    proj_kernel<<<dim3(32, T_STEPS), 256, 0, stream>>>(hs + (size_t)B_DIM * E_DIM,
                                                       Woutp, b_out, out);
}

// Round 5
// 333.326 us; speedup vs baseline: 3.3617x; 3.3617x over previous
//
#include <hip/hip_runtime.h>
#include <cstdint>
#include <cstddef>

#define E_DIM   1024
#define B_DIM   1024
#define T_STEPS 10
#define OUT_DIM 34
#define OUT_PAD 48
#define HSTR    24            // h-transpose LDS row stride (16 cols + pad)
#define QK      256           // k-elements per W quarter-slice
#define WQ_ELEMS (64 * QK)    // 16384 elems = 32 KB per buffer
#define DYN_LDS (2 * WQ_ELEMS * 2 + 128 * HSTR * 2)   // 65536 + 6144 = 71680 B

typedef __attribute__((ext_vector_type(4))) float  f32x4;
typedef __attribute__((ext_vector_type(8))) __bf16 bf16x8;

__device__ __forceinline__ unsigned short f2bf(float f) {
    unsigned int u = __float_as_uint(f);
    u = (u + 0x7FFFu + ((u >> 16) & 1u)) >> 16;   // round-to-nearest-even
    return (unsigned short)u;
}
__device__ __forceinline__ float sigmoid_(float x) { return 1.0f / (1.0f + __expf(-x)); }
__device__ __forceinline__ float tanh_(float x)    { return 2.0f / (1.0f + __expf(-2.0f * x)) - 1.0f; }

// Permutation: perm row n = 64*eb + 16*g + j  ->  gate g = (n>>4)&3, e = 16*eb + j.
// Block bn owns perm rows [64bn, 64bn+64) = 4 gates x 16 e-values; gate index == nt tile,
// so the LSTM epilogue is lane-local (acc[mt][gate][r]).
__global__ void prep_weights(const float* __restrict__ W_ih, const float* __restrict__ W_hh,
                             const float* __restrict__ b_ih, const float* __restrict__ b_hh,
                             unsigned short* __restrict__ Wsum, unsigned short* __restrict__ Whh,
                             float* __restrict__ bperm) {
    const int n = blockIdx.x;                       // 0..4095 permuted row
    const int g = (n >> 4) & 3;
    const int e = ((n >> 6) << 4) | (n & 15);
    const int srow = g * E_DIM + e;
    const size_t src = (size_t)srow * E_DIM;
    const int k = threadIdx.x * 4;
    float4 wi = *(const float4*)(W_ih + src + k);
    float4 wh = *(const float4*)(W_hh + src + k);
    const size_t dst = (size_t)n * E_DIM + k;
    Wsum[dst + 0] = f2bf(wi.x + wh.x);
    Wsum[dst + 1] = f2bf(wi.y + wh.y);
    Wsum[dst + 2] = f2bf(wi.z + wh.z);
    Wsum[dst + 3] = f2bf(wi.w + wh.w);
    Whh[dst + 0] = f2bf(wh.x);
    Whh[dst + 1] = f2bf(wh.y);
    Whh[dst + 2] = f2bf(wh.z);
    Whh[dst + 3] = f2bf(wh.w);
    if (threadIdx.x == 0) bperm[n] = b_ih[srow] + b_hh[srow];
}

// h0 -> bf16 into hs slot 0; W_out -> bf16 padded to 48 rows
__global__ void prep_state(const float* __restrict__ h0, const float* __restrict__ W_out,
                           unsigned short* __restrict__ hbuf, unsigned short* __restrict__ Woutp) {
    const int b = blockIdx.x;
    const int t = threadIdx.x;
    if (b < 1024) {
        const size_t i = ((size_t)b * 256 + t) * 4;
        float4 hv = *(const float4*)(h0 + i);
        hbuf[i + 0] = f2bf(hv.x);
        hbuf[i + 1] = f2bf(hv.y);
        hbuf[i + 2] = f2bf(hv.z);
        hbuf[i + 3] = f2bf(hv.w);
    } else {
        const int o = b - 1024;                     // 0..47
        const int k = t * 4;
        float4 w = make_float4(0.f, 0.f, 0.f, 0.f);
        if (o < OUT_DIM) w = *(const float4*)(W_out + (size_t)o * E_DIM + k);
        const size_t dst = (size_t)o * E_DIM + k;
        Woutp[dst + 0] = f2bf(w.x);
        Woutp[dst + 1] = f2bf(w.y);
        Woutp[dst + 2] = f2bf(w.z);
        Woutp[dst + 3] = f2bf(w.w);
    }
}

// Permute initial c into the MFMA-accumulator-native flat layout used by lstm_step:
// idx = (((bn*8+bm)*4 + wave)*64 + lane)*8 + mt*4 + r
// with m = bm*128 + wave*32 + mt*16 + q*4 + r, e = bn*16 + j, lane = q*16+j.
__global__ void prep_c(const float* __restrict__ c0, float* __restrict__ C) {
    const int m = blockIdx.x;
    const int e0 = threadIdx.x * 4;
    float4 v = *(const float4*)(c0 + (size_t)m * E_DIM + e0);
    const int bm = m >> 7, wave = (m >> 5) & 3, mt = (m >> 4) & 1, q = (m >> 2) & 3, r = m & 3;
    const float vv[4] = {v.x, v.y, v.z, v.w};
#pragma unroll
    for (int ii = 0; ii < 4; ++ii) {
        const int e = e0 + ii;
        const int bn = e >> 4, j = e & 15;
        const int lane = q * 16 + j;
        C[(((size_t)(bn * 8 + bm) * 4 + wave) * 64 + lane) * 8 + mt * 4 + r] = vv[ii];
    }
}

// One fused LSTM step. Grid (64, 8) = 512 blocks (2/CU), 256 threads = 4 waves.
// Block (bn,bm): 64 permuted N-rows (4 gates x 16 e) x 128 batch rows.
// W slice streamed through double-buffered quarter-K LDS (2 x 32 KB), staging
// loads issued a full quarter ahead; A (h) streamed global->reg, depth-8 pipeline.
__global__ __launch_bounds__(256, 2) void lstm_step(
    const unsigned short* __restrict__ Wp,   // [4096][1024] bf16 permuted
    const float* __restrict__ bp,            // [4096] permuted bias
    const unsigned short* __restrict__ Hin,  // [1024][1024] bf16
    float* __restrict__ C,                   // [B*E] f32 cell state in MFMA layout
    unsigned short* __restrict__ Hout)       // [1024][1024] bf16
{
    extern __shared__ __align__(16) unsigned short smem[];
    unsigned short* Wbuf0 = smem;                    // 32 KB
    unsigned short* Wbuf1 = smem + WQ_ELEMS;         // 32 KB
    unsigned short* Ht    = smem + 2 * WQ_ELEMS;     // 128 x HSTR (6 KB)

    const int tid  = threadIdx.x;
    const int wave = tid >> 6;
    const int lane = tid & 63;
    const int bn = blockIdx.x;
    const int bm = blockIdx.y;
    const int j  = lane & 15;
    const int q  = lane >> 4;
    const int j7 = j & 7;

    f32x4 acc[2][4];
#pragma unroll
    for (int a = 0; a < 2; ++a)
#pragma unroll
        for (int b = 0; b < 4; ++b) acc[a][b] = (f32x4){0.f, 0.f, 0.f, 0.f};

    // hoisted far-from-use loads: biases + old cell state
    const int nb = bn * 64 + j;
    const float bi = bp[nb +  0];
    const float bf = bp[nb + 16];
    const float bg = bp[nb + 32];
    const float bo = bp[nb + 48];
    const size_t cbase = (((size_t)(bn * 8 + bm) * 4 + wave) * 64 + lane) * 8;
    float4 cold0 = *(const float4*)(C + cbase);
    float4 cold1 = *(const float4*)(C + cbase + 4);

    // A row base (per mt): m = bm*128 + wave*32 + mt*16 + j
    const unsigned short* arow0 = Hin + (size_t)(bm * 128 + wave * 32 + j) * E_DIM + q * 8;
    const unsigned short* arow1 = arow0 + (size_t)16 * E_DIM;
    const unsigned short* wrow  = Wp + (size_t)(bn * 64) * E_DIM;

    // A pipeline, depth 8 (covers ~L2 latency)
    uint4 ra[8][2];
#pragma unroll
    for (int p = 0; p < 8; ++p) {
        ra[p][0] = *(const uint4*)(arow0 + p * 32);
        ra[p][1] = *(const uint4*)(arow1 + p * 32);
    }

    // stage quarter 0: 64 rows x 32 chunks(8 elem); chunk c stored at c^(row&7)
    uint4 wreg[8];
#pragma unroll
    for (int i = 0; i < 8; ++i) {
        const int s = i * 256 + tid, row = s >> 5, c = s & 31;
        wreg[i] = *(const uint4*)(wrow + (size_t)row * E_DIM + c * 8);
    }
#pragma unroll
    for (int i = 0; i < 8; ++i) {
        const int s = i * 256 + tid, row = s >> 5, c = s & 31;
        *(uint4*)(Wbuf0 + row * QK + ((c ^ (row & 7)) << 3)) = wreg[i];
    }
    __syncthreads();

    for (int qtr = 0; qtr < 4; ++qtr) {
        // issue next quarter's global loads early (consumed at quarter end)
        if (qtr < 3) {
#pragma unroll
            for (int i = 0; i < 8; ++i) {
                const int s = i * 256 + tid, row = s >> 5, c = s & 31;
                wreg[i] = *(const uint4*)(wrow + (size_t)row * E_DIM + (qtr + 1) * QK + c * 8);
            }
        }
        const unsigned short* wb = (qtr & 1) ? Wbuf1 : Wbuf0;
#pragma unroll
        for (int ks8 = 0; ks8 < 8; ++ks8) {
            const int ks = qtr * 8 + ks8;
            bf16x8 av0 = __builtin_bit_cast(bf16x8, ra[ks & 7][0]);
            bf16x8 av1 = __builtin_bit_cast(bf16x8, ra[ks & 7][1]);
            const int coff = ((ks8 * 4 + q) ^ j7) << 3;   // uniform bank spread
            bf16x8 bv[4];
#pragma unroll
            for (int nt = 0; nt < 4; ++nt)
                bv[nt] = *(const bf16x8*)(wb + (nt * 16 + j) * QK + coff);
#pragma unroll
            for (int nt = 0; nt < 4; ++nt) {
                acc[0][nt] = __builtin_amdgcn_mfma_f32_16x16x32_bf16(av0, bv[nt], acc[0][nt], 0, 0, 0);
                acc[1][nt] = __builtin_amdgcn_mfma_f32_16x16x32_bf16(av1, bv[nt], acc[1][nt], 0, 0, 0);
            }
            if (ks < 24) {                  // keep the 8-deep A pipeline full
                ra[ks & 7][0] = *(const uint4*)(arow0 + (ks + 8) * 32);
                ra[ks & 7][1] = *(const uint4*)(arow1 + (ks + 8) * 32);
            }
        }
        if (qtr < 3) {
            unsigned short* wn_ = ((qtr + 1) & 1) ? Wbuf1 : Wbuf0;
#pragma unroll
            for (int i = 0; i < 8; ++i) {
                const int s = i * 256 + tid, row = s >> 5, c = s & 31;
                *(uint4*)(wn_ + row * QK + ((c ^ (row & 7)) << 3)) = wreg[i];
            }
            __syncthreads();
        }
    }

    // ---- Epilogue: nt is the gate index (i,f,g,o); lane-local LSTM update ----
    float4 cnew[2];
    const float coldv[2][4] = {{cold0.x, cold0.y, cold0.z, cold0.w},
                               {cold1.x, cold1.y, cold1.z, cold1.w}};
#pragma unroll
    for (int mt = 0; mt < 2; ++mt) {
#pragma unroll
        for (int r = 0; r < 4; ++r) {
            const float iv = sigmoid_(acc[mt][0][r] + bi);
            const float fv = sigmoid_(acc[mt][1][r] + bf);
            const float gv = tanh_(acc[mt][2][r] + bg);
            const float ov = sigmoid_(acc[mt][3][r] + bo);
            const float cn = fv * coldv[mt][r] + iv * gv;
            cnew[mt][r] = cn;
            const int rowl = wave * 32 + mt * 16 + q * 4 + r;   // 0..127
            Ht[rowl * HSTR + j] = f2bf(ov * tanh_(cn));
        }
    }
    *(float4*)(C + cbase)     = cnew[0];
    *(float4*)(C + cbase + 4) = cnew[1];
    __syncthreads();

    // coalesced h store: 2 threads per row, 16B each
    {
        const int row = tid >> 1, part = tid & 1;
        uint4 v = *(const uint4*)(Ht + row * HSTR + part * 8);
        *(uint4*)(Hout + (size_t)(bm * 128 + row) * E_DIM + bn * 16 + part * 8) = v;
    }
}

// Output projection: out[b,t,o] = hs[t+1][b][:] . Wo[o][:] + b_out[o]
// Grid (32, 10) = 320 blocks, 256 thr = 4 waves; wave w covers K-quarter [w*256,+256),
// block covers 32 batch rows x 48 (padded) outputs; cross-wave LDS reduction.
__global__ __launch_bounds__(256) void proj_kernel(
    const unsigned short* __restrict__ Hs,   // [T][B][E] bf16 (slot 1 of hs)
    const unsigned short* __restrict__ Wo,   // [48][E] bf16 (rows >=34 zero)
    const float* __restrict__ b_out,         // [34]
    float* __restrict__ Out)                 // [B][T][34]
{
    __shared__ float red[4][32][OUT_PAD];    // 24 KB

    const int tid = threadIdx.x, wave = tid >> 6, lane = tid & 63;
    const int j = lane & 15, q = lane >> 4;
    const int t  = blockIdx.y;
    const int bb = blockIdx.x;
    const unsigned short* Hbase = Hs + ((size_t)t * B_DIM + (size_t)bb * 32) * E_DIM;
    const int k0 = wave * 256;

    f32x4 acc[2][3];
#pragma unroll
    for (int a = 0; a < 2; ++a)
#pragma unroll
        for (int b = 0; b < 3; ++b) acc[a][b] = (f32x4){0.f, 0.f, 0.f, 0.f};

#pragma unroll
    for (int kk = 0; kk < 256; kk += 32) {
        const int kc = k0 + kk + q * 8;
        bf16x8 av[2], bv[3];
#pragma unroll
        for (int mt = 0; mt < 2; ++mt)
            av[mt] = *(const bf16x8*)(Hbase + (size_t)(mt * 16 + j) * E_DIM + kc);
#pragma unroll
        for (int nt = 0; nt < 3; ++nt)
            bv[nt] = *(const bf16x8*)(Wo + (size_t)(nt * 16 + j) * E_DIM + kc);
#pragma unroll
        for (int mt = 0; mt < 2; ++mt)
#pragma unroll
            for (int nt = 0; nt < 3; ++nt)
                acc[mt][nt] = __builtin_amdgcn_mfma_f32_16x16x32_bf16(av[mt], bv[nt], acc[mt][nt], 0, 0, 0);
    }

#pragma unroll
    for (int mt = 0; mt < 2; ++mt)
#pragma unroll
        for (int nt = 0; nt < 3; ++nt)
#pragma unroll
            for (int r = 0; r < 4; ++r)
                red[wave][mt * 16 + q * 4 + r][nt * 16 + j] = acc[mt][nt][r];
    __syncthreads();

#pragma unroll
    for (int ii = 0; ii < 6; ++ii) {
        const int idx = tid * 6 + ii;            // 0..1535 = 32 rows x 48 outs
        const int row = idx / OUT_PAD, o = idx % OUT_PAD;
        if (o < OUT_DIM) {
            const float s = red[0][row][o] + red[1][row][o] + red[2][row][o] + red[3][row][o];
            Out[((size_t)(bb * 32 + row) * T_STEPS + t) * OUT_DIM + o] = s + b_out[o];
        }
    }
}

extern "C" void kernel_launch(void* const* d_in, const int* in_sizes, int n_in,
                              void* d_out, int out_size, void* d_ws, size_t ws_size,
                              hipStream_t stream) {
    (void)in_sizes; (void)n_in; (void)out_size; (void)ws_size;
    const float* h     = (const float*)d_in[0];
    const float* c     = (const float*)d_in[1];
    const float* W_ih  = (const float*)d_in[2];
    const float* W_hh  = (const float*)d_in[3];
    const float* b_ih  = (const float*)d_in[4];
    const float* b_hh  = (const float*)d_in[5];
    const float* W_out = (const float*)d_in[6];
    const float* b_out = (const float*)d_in[7];
    float* out = (float*)d_out;

    char* ws = (char*)d_ws;
    unsigned short* Wsum  = (unsigned short*)(ws + 0);          //  8 MB
    unsigned short* Whh   = (unsigned short*)(ws + 8388608);    //  8 MB
    float*          bperm = (float*)(ws + 16777216);            // 16 KB
    unsigned short* Woutp = (unsigned short*)(ws + 16842752);   // 96 KB
    float*          cbuf  = (float*)(ws + 16941056);            //  4 MB (MFMA layout)
    unsigned short* hs    = (unsigned short*)(ws + 21135360);   // 22 MB: slot0=h0, slots1..10

    // host-side attribute set (not a stream op; safe under graph capture)
    hipFuncSetAttribute((const void*)lstm_step,
                        hipFuncAttributeMaxDynamicSharedMemorySize, DYN_LDS);

    prep_weights<<<4096, 256, 0, stream>>>(W_ih, W_hh, b_ih, b_hh, Wsum, Whh, bperm);
    prep_state<<<1072, 256, 0, stream>>>(h, W_out, hs, Woutp);
    prep_c<<<1024, 256, 0, stream>>>(c, cbuf);

    // step 0: x = 0  ->  W_hh only; steps 1..9: x == h_prev -> fused W_ih + W_hh
    lstm_step<<<dim3(64, 8), 256, DYN_LDS, stream>>>(Whh, bperm, hs, cbuf,
                                                     hs + (size_t)B_DIM * E_DIM);
    for (int t = 1; t < T_STEPS; ++t)
        lstm_step<<<dim3(64, 8), 256, DYN_LDS, stream>>>(Wsum, bperm,
                                                         hs + (size_t)t * B_DIM * E_DIM,
                                                         cbuf,
                                                         hs + (size_t)(t + 1) * B_DIM * E_DIM);

    proj_kernel<<<dim3(32, T_STEPS), 256, 0, stream>>>(hs + (size_t)B_DIM * E_DIM,
                                                       Woutp, b_out, out);
}

// Round 6
// 329.451 us; speedup vs baseline: 3.4013x; 1.0118x over previous
//
#include <hip/hip_runtime.h>
#include <cstdint>
#include <cstddef>

#define E_DIM   1024
#define B_DIM   1024
#define T_STEPS 10
#define OUT_DIM 34
#define OUT_PAD 48
#define HSTR    24            // h-transpose LDS row stride (16 cols + pad)
#define QK      256           // k-elements per W quarter-slice
#define WQ_ELEMS (64 * QK)    // 16384 elems = 32 KB per buffer
#define DYN_LDS (2 * WQ_ELEMS * 2 + 128 * HSTR * 2)   // 65536 + 6144 = 71680 B

typedef __attribute__((ext_vector_type(4))) float  f32x4;
typedef __attribute__((ext_vector_type(8))) __bf16 bf16x8;

__device__ __forceinline__ unsigned short f2bf(float f) {
    unsigned int u = __float_as_uint(f);
    u = (u + 0x7FFFu + ((u >> 16) & 1u)) >> 16;   // round-to-nearest-even
    return (unsigned short)u;
}
__device__ __forceinline__ float sigmoid_(float x) { return 1.0f / (1.0f + __expf(-x)); }
__device__ __forceinline__ float tanh_(float x)    { return 2.0f / (1.0f + __expf(-2.0f * x)) - 1.0f; }

// Weights emitted directly in MFMA-B-fragment order:
//   WF[bn(64)][qtr(4)][ks8(8)][nt(4)][lane(64)][8 elems]
// frag element: n-row = gate nt, e = bn*16 + (lane&15); k = qtr*256 + ks8*32 + (lane>>4)*8 + e8.
// In lstm_step this makes LDS staging a linear copy and the B-read `base + lane*16B`
// with a static immediate offset -> conflict-free (2-way only) and zero address VALU.
__global__ void prep_weights_frag(const float* __restrict__ W_ih, const float* __restrict__ W_hh,
                                  unsigned short* __restrict__ WsumF, unsigned short* __restrict__ WhhF) {
    const int bn = blockIdx.x >> 2, qtr = blockIdx.x & 3;
    const int nt = threadIdx.x >> 6, lane = threadIdx.x & 63;
    const int j = lane & 15, q = lane >> 4;
    const int srow = nt * E_DIM + bn * 16 + j;
    const float* wi = W_ih + (size_t)srow * E_DIM;
    const float* wh = W_hh + (size_t)srow * E_DIM;
    const size_t dstb = (size_t)bn * 65536 + (size_t)qtr * 16384 + nt * 512 + lane * 8;
#pragma unroll
    for (int ks8 = 0; ks8 < 8; ++ks8) {
        const int k = qtr * 256 + ks8 * 32 + q * 8;
        float4 i0 = *(const float4*)(wi + k);
        float4 i1 = *(const float4*)(wi + k + 4);
        float4 h0 = *(const float4*)(wh + k);
        float4 h1 = *(const float4*)(wh + k + 4);
        unsigned short* ds = WsumF + dstb + ks8 * 2048;
        unsigned short* dh = WhhF  + dstb + ks8 * 2048;
        ds[0] = f2bf(i0.x + h0.x); ds[1] = f2bf(i0.y + h0.y);
        ds[2] = f2bf(i0.z + h0.z); ds[3] = f2bf(i0.w + h0.w);
        ds[4] = f2bf(i1.x + h1.x); ds[5] = f2bf(i1.y + h1.y);
        ds[6] = f2bf(i1.z + h1.z); ds[7] = f2bf(i1.w + h1.w);
        dh[0] = f2bf(h0.x); dh[1] = f2bf(h0.y); dh[2] = f2bf(h0.z); dh[3] = f2bf(h0.w);
        dh[4] = f2bf(h1.x); dh[5] = f2bf(h1.y); dh[6] = f2bf(h1.z); dh[7] = f2bf(h1.w);
    }
}

// h0 -> bf16 into hs slot 0; W_out -> bf16 padded to 48 rows; bias permuted
// (bperm[n], n = bn*64 + 16*g + j  <-  b_ih[g*1024 + bn*16 + j] + b_hh[same])
__global__ void prep_state(const float* __restrict__ h0, const float* __restrict__ W_out,
                           const float* __restrict__ b_ih, const float* __restrict__ b_hh,
                           unsigned short* __restrict__ hbuf, unsigned short* __restrict__ Woutp,
                           float* __restrict__ bperm) {
    const int b = blockIdx.x;
    const int t = threadIdx.x;
    if (b < 1024) {
        const size_t i = ((size_t)b * 256 + t) * 4;
        float4 hv = *(const float4*)(h0 + i);
        hbuf[i + 0] = f2bf(hv.x);
        hbuf[i + 1] = f2bf(hv.y);
        hbuf[i + 2] = f2bf(hv.z);
        hbuf[i + 3] = f2bf(hv.w);
    } else if (b < 1072) {
        const int o = b - 1024;                     // 0..47
        const int k = t * 4;
        float4 w = make_float4(0.f, 0.f, 0.f, 0.f);
        if (o < OUT_DIM) w = *(const float4*)(W_out + (size_t)o * E_DIM + k);
        const size_t dst = (size_t)o * E_DIM + k;
        Woutp[dst + 0] = f2bf(w.x);
        Woutp[dst + 1] = f2bf(w.y);
        Woutp[dst + 2] = f2bf(w.z);
        Woutp[dst + 3] = f2bf(w.w);
    } else {
        const int n = (b - 1072) * 256 + t;         // 0..4095
        const int g = (n >> 4) & 3;
        const int e = ((n >> 6) << 4) | (n & 15);
        const int srow = g * E_DIM + e;
        bperm[n] = b_ih[srow] + b_hh[srow];
    }
}

// Permute initial c into the MFMA-accumulator-native flat layout used by lstm_step:
// idx = (((bn*8+bm)*4 + wave)*64 + lane)*8 + mt*4 + r
// with m = bm*128 + wave*32 + mt*16 + q*4 + r, e = bn*16 + j, lane = q*16+j.
__global__ void prep_c(const float* __restrict__ c0, float* __restrict__ C) {
    const int m = blockIdx.x;
    const int e0 = threadIdx.x * 4;
    float4 v = *(const float4*)(c0 + (size_t)m * E_DIM + e0);
    const int bm = m >> 7, wave = (m >> 5) & 3, mt = (m >> 4) & 1, q = (m >> 2) & 3, r = m & 3;
    const float vv[4] = {v.x, v.y, v.z, v.w};
#pragma unroll
    for (int ii = 0; ii < 4; ++ii) {
        const int e = e0 + ii;
        const int bn = e >> 4, j = e & 15;
        const int lane = q * 16 + j;
        C[(((size_t)(bn * 8 + bm) * 4 + wave) * 64 + lane) * 8 + mt * 4 + r] = vv[ii];
    }
}

// One fused LSTM step. Grid (64, 8) = 512 blocks (2/CU), 256 threads = 4 waves.
// Block (bn,bm): 64 permuted N-rows (4 gates x 16 e) x 128 batch rows.
// W streamed through double-buffered quarter-K LDS in fragment-linear order:
// staging = linear copy; B-read = base + lane*16B + imm -> conflict-free, no addr VALU.
__global__ __launch_bounds__(256, 2) void lstm_step(
    const unsigned short* __restrict__ WF,   // [64][4][8][4][64][8] bf16 fragment-order
    const float* __restrict__ bp,            // [4096] permuted bias
    const unsigned short* __restrict__ Hin,  // [1024][1024] bf16
    float* __restrict__ C,                   // [B*E] f32 cell state in MFMA layout
    unsigned short* __restrict__ Hout)       // [1024][1024] bf16
{
    extern __shared__ __align__(16) unsigned short smem[];
    unsigned short* Wbuf0 = smem;                    // 32 KB
    unsigned short* Wbuf1 = smem + WQ_ELEMS;         // 32 KB
    unsigned short* Ht    = smem + 2 * WQ_ELEMS;     // 128 x HSTR (6 KB)

    const int tid  = threadIdx.x;
    const int wave = tid >> 6;
    const int lane = tid & 63;
    const int bn = blockIdx.x;
    const int bm = blockIdx.y;
    const int j  = lane & 15;
    const int q  = lane >> 4;

    f32x4 acc[2][4];
#pragma unroll
    for (int a = 0; a < 2; ++a)
#pragma unroll
        for (int b = 0; b < 4; ++b) acc[a][b] = (f32x4){0.f, 0.f, 0.f, 0.f};

    // hoisted far-from-use loads: biases + old cell state
    const int nb = bn * 64 + j;
    const float bi = bp[nb +  0];
    const float bf = bp[nb + 16];
    const float bg = bp[nb + 32];
    const float bo = bp[nb + 48];
    const size_t cbase = (((size_t)(bn * 8 + bm) * 4 + wave) * 64 + lane) * 8;
    float4 cold0 = *(const float4*)(C + cbase);
    float4 cold1 = *(const float4*)(C + cbase + 4);

    // A row base (per mt): m = bm*128 + wave*32 + mt*16 + j
    const unsigned short* arow0 = Hin + (size_t)(bm * 128 + wave * 32 + j) * E_DIM + q * 8;
    const unsigned short* arow1 = arow0 + (size_t)16 * E_DIM;
    const unsigned short* wsrc  = WF + (size_t)bn * 65536;    // this block's 128 KB slice

    // A pipeline, depth 8 (covers ~L2 latency)
    uint4 ra[8][2];
#pragma unroll
    for (int p = 0; p < 8; ++p) {
        ra[p][0] = *(const uint4*)(arow0 + p * 32);
        ra[p][1] = *(const uint4*)(arow1 + p * 32);
    }

    // stage quarter 0: pure linear copy, 256 threads x 8 x 16 B
    uint4 wreg[8];
#pragma unroll
    for (int i = 0; i < 8; ++i)
        wreg[i] = *(const uint4*)(wsrc + (i * 256 + tid) * 8);
#pragma unroll
    for (int i = 0; i < 8; ++i)
        *(uint4*)(Wbuf0 + (i * 256 + tid) * 8) = wreg[i];
    __syncthreads();

    for (int qtr = 0; qtr < 4; ++qtr) {
        // issue next quarter's global loads early (consumed at quarter end)
        if (qtr < 3) {
#pragma unroll
            for (int i = 0; i < 8; ++i)
                wreg[i] = *(const uint4*)(wsrc + (size_t)(qtr + 1) * WQ_ELEMS + (i * 256 + tid) * 8);
        }
        const unsigned short* wb = ((qtr & 1) ? Wbuf1 : Wbuf0) + lane * 8;
#pragma unroll
        for (int ks8 = 0; ks8 < 8; ++ks8) {
            const int ks = qtr * 8 + ks8;
            bf16x8 av0 = __builtin_bit_cast(bf16x8, ra[ks8][0]);
            bf16x8 av1 = __builtin_bit_cast(bf16x8, ra[ks8][1]);
            bf16x8 bv[4];
#pragma unroll
            for (int nt = 0; nt < 4; ++nt)
                bv[nt] = *(const bf16x8*)(wb + (ks8 * 4 + nt) * 512);   // imm offset, lane*16B base
#pragma unroll
            for (int nt = 0; nt < 4; ++nt) {
                acc[0][nt] = __builtin_amdgcn_mfma_f32_16x16x32_bf16(av0, bv[nt], acc[0][nt], 0, 0, 0);
                acc[1][nt] = __builtin_amdgcn_mfma_f32_16x16x32_bf16(av1, bv[nt], acc[1][nt], 0, 0, 0);
            }
            if (ks < 24) {                  // keep the 8-deep A pipeline full
                ra[ks8][0] = *(const uint4*)(arow0 + (ks + 8) * 32);
                ra[ks8][1] = *(const uint4*)(arow1 + (ks + 8) * 32);
            }
        }
        if (qtr < 3) {
            unsigned short* wn_ = ((qtr + 1) & 1) ? Wbuf1 : Wbuf0;
#pragma unroll
            for (int i = 0; i < 8; ++i)
                *(uint4*)(wn_ + (i * 256 + tid) * 8) = wreg[i];
            __syncthreads();
        }
    }

    // ---- Epilogue: nt is the gate index (i,f,g,o); lane-local LSTM update ----
    float4 cnew[2];
    const float coldv[2][4] = {{cold0.x, cold0.y, cold0.z, cold0.w},
                               {cold1.x, cold1.y, cold1.z, cold1.w}};
#pragma unroll
    for (int mt = 0; mt < 2; ++mt) {
#pragma unroll
        for (int r = 0; r < 4; ++r) {
            const float iv = sigmoid_(acc[mt][0][r] + bi);
            const float fv = sigmoid_(acc[mt][1][r] + bf);
            const float gv = tanh_(acc[mt][2][r] + bg);
            const float ov = sigmoid_(acc[mt][3][r] + bo);
            const float cn = fv * coldv[mt][r] + iv * gv;
            cnew[mt][r] = cn;
            const int rowl = wave * 32 + mt * 16 + q * 4 + r;   // 0..127
            Ht[rowl * HSTR + j] = f2bf(ov * tanh_(cn));
        }
    }
    *(float4*)(C + cbase)     = cnew[0];
    *(float4*)(C + cbase + 4) = cnew[1];
    __syncthreads();

    // coalesced h store: 2 threads per row, 16B each
    {
        const int row = tid >> 1, part = tid & 1;
        uint4 v = *(const uint4*)(Ht + row * HSTR + part * 8);
        *(uint4*)(Hout + (size_t)(bm * 128 + row) * E_DIM + bn * 16 + part * 8) = v;
    }
}

// Output projection: out[b,t,o] = hs[t+1][b][:] . Wo[o][:] + b_out[o]
// Grid (32, 10) = 320 blocks, 256 thr = 4 waves; wave w covers K-quarter [w*256,+256),
// block covers 32 batch rows x 48 (padded) outputs; cross-wave LDS reduction.
__global__ __launch_bounds__(256) void proj_kernel(
    const unsigned short* __restrict__ Hs,   // [T][B][E] bf16 (slot 1 of hs)
    const unsigned short* __restrict__ Wo,   // [48][E] bf16 (rows >=34 zero)
    const float* __restrict__ b_out,         // [34]
    float* __restrict__ Out)                 // [B][T][34]
{
    __shared__ float red[4][32][OUT_PAD];    // 24 KB

    const int tid = threadIdx.x, wave = tid >> 6, lane = tid & 63;
    const int j = lane & 15, q = lane >> 4;
    const int t  = blockIdx.y;
    const int bb = blockIdx.x;
    const unsigned short* Hbase = Hs + ((size_t)t * B_DIM + (size_t)bb * 32) * E_DIM;
    const int k0 = wave * 256;

    f32x4 acc[2][3];
#pragma unroll
    for (int a = 0; a < 2; ++a)
#pragma unroll
        for (int b = 0; b < 3; ++b) acc[a][b] = (f32x4){0.f, 0.f, 0.f, 0.f};

#pragma unroll
    for (int kk = 0; kk < 256; kk += 32) {
        const int kc = k0 + kk + q * 8;
        bf16x8 av[2], bv[3];
#pragma unroll
        for (int mt = 0; mt < 2; ++mt)
            av[mt] = *(const bf16x8*)(Hbase + (size_t)(mt * 16 + j) * E_DIM + kc);
#pragma unroll
        for (int nt = 0; nt < 3; ++nt)
            bv[nt] = *(const bf16x8*)(Wo + (size_t)(nt * 16 + j) * E_DIM + kc);
#pragma unroll
        for (int mt = 0; mt < 2; ++mt)
#pragma unroll
            for (int nt = 0; nt < 3; ++nt)
                acc[mt][nt] = __builtin_amdgcn_mfma_f32_16x16x32_bf16(av[mt], bv[nt], acc[mt][nt], 0, 0, 0);
    }

#pragma unroll
    for (int mt = 0; mt < 2; ++mt)
#pragma unroll
        for (int nt = 0; nt < 3; ++nt)
#pragma unroll
            for (int r = 0; r < 4; ++r)
                red[wave][mt * 16 + q * 4 + r][nt * 16 + j] = acc[mt][nt][r];
    __syncthreads();

#pragma unroll
    for (int ii = 0; ii < 6; ++ii) {
        const int idx = tid * 6 + ii;            // 0..1535 = 32 rows x 48 outs
        const int row = idx / OUT_PAD, o = idx % OUT_PAD;
        if (o < OUT_DIM) {
            const float s = red[0][row][o] + red[1][row][o] + red[2][row][o] + red[3][row][o];
            Out[((size_t)(bb * 32 + row) * T_STEPS + t) * OUT_DIM + o] = s + b_out[o];
        }
    }
}

extern "C" void kernel_launch(void* const* d_in, const int* in_sizes, int n_in,
                              void* d_out, int out_size, void* d_ws, size_t ws_size,
                              hipStream_t stream) {
    (void)in_sizes; (void)n_in; (void)out_size; (void)ws_size;
    const float* h     = (const float*)d_in[0];
    const float* c     = (const float*)d_in[1];
    const float* W_ih  = (const float*)d_in[2];
    const float* W_hh  = (const float*)d_in[3];
    const float* b_ih  = (const float*)d_in[4];
    const float* b_hh  = (const float*)d_in[5];
    const float* W_out = (const float*)d_in[6];
    const float* b_out = (const float*)d_in[7];
    float* out = (float*)d_out;

    char* ws = (char*)d_ws;
    unsigned short* WsumF = (unsigned short*)(ws + 0);          //  8 MB fragment-order
    unsigned short* WhhF  = (unsigned short*)(ws + 8388608);    //  8 MB fragment-order
    float*          bperm = (float*)(ws + 16777216);            // 16 KB
    unsigned short* Woutp = (unsigned short*)(ws + 16842752);   // 96 KB
    float*          cbuf  = (float*)(ws + 16941056);            //  4 MB (MFMA layout)
    unsigned short* hs    = (unsigned short*)(ws + 21135360);   // 22 MB: slot0=h0, slots1..10

    // host-side attribute set (not a stream op; safe under graph capture)
    hipFuncSetAttribute((const void*)lstm_step,
                        hipFuncAttributeMaxDynamicSharedMemorySize, DYN_LDS);

    prep_weights_frag<<<256, 256, 0, stream>>>(W_ih, W_hh, WsumF, WhhF);
    prep_state<<<1088, 256, 0, stream>>>(h, W_out, b_ih, b_hh, hs, Woutp, bperm);
    prep_c<<<1024, 256, 0, stream>>>(c, cbuf);

    // step 0: x = 0  ->  W_hh only; steps 1..9: x == h_prev -> fused W_ih + W_hh
    lstm_step<<<dim3(64, 8), 256, DYN_LDS, stream>>>(WhhF, bperm, hs, cbuf,
                                                     hs + (size_t)B_DIM * E_DIM);
    for (int t = 1; t < T_STEPS; ++t)
        lstm_step<<<dim3(64, 8), 256, DYN_LDS, stream>>>(WsumF, bperm,
                                                         hs + (size_t)t * B_DIM * E_DIM,
                                                         cbuf,
                                                         hs + (size_t)(t + 1) * B_DIM * E_DIM);

    proj_kernel<<<dim3(32, T_STEPS), 256, 0, stream>>>(hs + (size_t)B_DIM * E_DIM,
                                                       Woutp, b_out, out);
}